// Round 3
// baseline (627.270 us; speedup 1.0000x reference)
//
#include <hip/hip_runtime.h>
#include <math.h>

#define T_LEN 65536

#define DROW 72      // bf16 words per staged data row (64 + 8 pad; rows 16B-aligned)
#define SLOT_A 324   // f32 words per A tile slot (16 rows x 20 + 4 pad); groups on disjoint banks
#define RS_A 20      // f32 row stride inside A tile (16B-aligned rows)
#define SLOT_B 280   // bf16 words per B tile slot (16 rows x 16 + 8 pad); 560B stagger
#define K2 64        // stage-2 chunk length
#define W2 32        // stage-2 warm-up steps
#define PF 8         // stage-2 prefetch depth

typedef __attribute__((ext_vector_type(8))) short bh8;
typedef __attribute__((ext_vector_type(4))) float f4;

__device__ __forceinline__ unsigned short f2bf(float x) {
    union { float f; unsigned u; } v; v.f = x;
    return (unsigned short)((v.u + 0x7FFFu + ((v.u >> 16) & 1u)) >> 16);  // RNE
}
__device__ __forceinline__ float bf2f(unsigned short s) {
    union { unsigned u; float f; } v; v.u = ((unsigned)s) << 16; return v.f;
}

// ---- one-time weight swizzle into bf16 MFMA B-fragment order ----
// frag f = job*2 + ks (job 0..32, ks 0..1); element (lane, j):
//   B[k][n], k = ks*32 + (lane>>4)*8 + j, n = job*16 + (lane&15)
__global__ void wswz_kernel(const float* __restrict__ Wmu, const float* __restrict__ WL,
                            const float* __restrict__ WLx, short* __restrict__ Wsw)
{
    int idx = blockIdx.x * 256 + threadIdx.x;   // 0 .. 66*512-1
    int f = idx >> 9, r = idx & 511;
    int lane = r >> 3, j = r & 7;
    int ks = f & 1, job = f >> 1;
    int k = ks * 32 + ((lane >> 4) << 3) + j;
    int n = job * 16 + (lane & 15);
    float v = (n < 16) ? Wmu[k * 16 + n]
            : (n < 272) ? WL[k * 256 + (n - 16)]
            : WLx[k * 256 + (n - 272)];
    Wsw[idx] = (short)f2bf(v);
}

// ---- fused: MFMA recognition GEMM -> LDS -> per-t factorization ----
__global__ __launch_bounds__(256, 5)
void vilds_fused(const float* __restrict__ data, const short* __restrict__ Wsw,
                 const float* __restrict__ bmu, const float* __restrict__ bL,
                 const float* __restrict__ bLx, const float* __restrict__ ns,
                 unsigned short* __restrict__ Nbuf, float* __restrict__ Ubuf,
                 float* __restrict__ PXbuf, float* __restrict__ entOut)
{
    __shared__ short Dt[17 * DROW];        // data rows t0..t0+16, bf16
    __shared__ float Atl[16 * SLOT_A];     // AAChol tiles f32 (later overwritten by P)
    __shared__ short Btl[16 * SLOT_B];     // BBChol tiles bf16

    const int tid = threadIdx.x;
    const int t0 = blockIdx.x * 16;

    // stage data rows t0..t0+16 as bf16 (row t0+16 needed for BBChol of t0+15)
    for (int idx = tid; idx < 17 * 16; idx += 256) {
        int row = idx >> 4, c4 = idx & 15;
        int tr = t0 + row;
        float4 dv = (tr < T_LEN) ? ((const float4*)data)[(size_t)tr * 16 + c4]
                                 : make_float4(0.f, 0.f, 0.f, 0.f);
        short4 b;
        b.x = (short)f2bf(dv.x); b.y = (short)f2bf(dv.y);
        b.z = (short)f2bf(dv.z); b.w = (short)f2bf(dv.w);
        *(short4*)&Dt[row * DROW + c4 * 4] = b;
    }
    __syncthreads();

    // ---- MFMA phase: jobs 0=postX, 1..16=A rows, 17..32=B rows ----
    {
        const int wv = tid >> 6, lane = tid & 63;
        const int col = lane & 15, quad = lane >> 4;
        // A-operand fragments (reused across all jobs): rowoff 0 (A/postX), 1 (B)
        bh8 a00 = *(const bh8*)&Dt[col * DROW + quad * 8];
        bh8 a01 = *(const bh8*)&Dt[col * DROW + quad * 8 + 32];
        bh8 a10 = *(const bh8*)&Dt[(col + 1) * DROW + quad * 8];
        bh8 a11 = *(const bh8*)&Dt[(col + 1) * DROW + quad * 8 + 32];
        for (int job = wv; job < 33; job += 4) {
            const int isB = (job >= 17);
            bh8 b0 = *(const bh8*)&Wsw[(job * 2 + 0) * 512 + lane * 8];
            bh8 b1 = *(const bh8*)&Wsw[(job * 2 + 1) * 512 + lane * 8];
            float bias;
            if (job == 0)      bias = bmu[col];
            else if (!isB)     bias = bL[(job - 1) * 16 + col] + ((col == job - 1) ? 3.0f : 0.0f);
            else               bias = bLx[(job - 17) * 16 + col];
            f4 acc = { bias, bias, bias, bias };
            acc = __builtin_amdgcn_mfma_f32_16x16x32_bf16(isB ? a10 : a00, b0, acc, 0, 0, 0);
            acc = __builtin_amdgcn_mfma_f32_16x16x32_bf16(isB ? a11 : a01, b1, acc, 0, 0, 0);
            // D layout: row = quad*4+r (t within block), col = lane&15
            if (job == 0) {
                #pragma unroll
                for (int r = 0; r < 4; ++r)
                    PXbuf[(size_t)(t0 + quad * 4 + r) * 16 + col] = acc[r];
            } else if (!isB) {
                int i = job - 1;
                #pragma unroll
                for (int r = 0; r < 4; ++r)
                    Atl[(quad * 4 + r) * SLOT_A + i * RS_A + col] = acc[r];
            } else {
                int i = job - 17;
                #pragma unroll
                for (int r = 0; r < 4; ++r)
                    Btl[(quad * 4 + r) * SLOT_B + i * 16 + col] = (short)f2bf(acc[r]);
            }
        }
    }
    __syncthreads();

    // ---- factorization: group gg (16 lanes, one wave) handles t = t0+gg ----
    const int gg = tid >> 4, li = tid & 15;
    const int t = t0 + gg;
    float* At = &Atl[gg * SLOT_A];
    const short* Bt_ = &Btl[gg * SLOT_B];

    // own A row
    float a[16];
    #pragma unroll
    for (int c = 0; c < 4; ++c) {
        f4 v = *(const f4*)&At[li * RS_A + c * 4];
        a[4*c+0] = v[0]; a[4*c+1] = v[1]; a[4*c+2] = v[2]; a[4*c+3] = v[3];
    }

    // S = A A^T + 1e-6 I, row li
    float s[16];
    #pragma unroll
    for (int j = 0; j < 16; ++j) {
        f4 r0 = *(const f4*)&At[j * RS_A + 0];
        f4 r1 = *(const f4*)&At[j * RS_A + 4];
        f4 r2 = *(const f4*)&At[j * RS_A + 8];
        f4 r3 = *(const f4*)&At[j * RS_A + 12];
        float acc = (j == li) ? 1e-6f : 0.0f;
        acc = fmaf(a[0], r0[0], acc);  acc = fmaf(a[1], r0[1], acc);
        acc = fmaf(a[2], r0[2], acc);  acc = fmaf(a[3], r0[3], acc);
        acc = fmaf(a[4], r1[0], acc);  acc = fmaf(a[5], r1[1], acc);
        acc = fmaf(a[6], r1[2], acc);  acc = fmaf(a[7], r1[3], acc);
        acc = fmaf(a[8], r2[0], acc);  acc = fmaf(a[9], r2[1], acc);
        acc = fmaf(a[10], r2[2], acc); acc = fmaf(a[11], r2[3], acc);
        acc = fmaf(a[12], r3[0], acc); acc = fmaf(a[13], r3[1], acc);
        acc = fmaf(a[14], r3[2], acc); acc = fmaf(a[15], r3[3], acc);
        s[j] = acc;
    }

    // Cholesky G of S (lane li owns row li), shuffle-based
    float gr[16], invd[16];
    float ent = 0.0f;
    #pragma unroll
    for (int k = 0; k < 16; ++k) {
        float dkk = __shfl(s[k], k, 16);
        dkk = fmaxf(dkk, 1e-20f);
        if (li == k) ent += 0.5f * logf(dkk);
        float inv = 1.0f / sqrtf(dkk);
        invd[k] = inv;
        gr[k] = s[k] * inv;                    // G[li][k], valid li>=k
        #pragma unroll
        for (int j = k + 1; j < 16; ++j) {
            float bcj = __shfl(gr[k], j, 16);  // G[j][k]
            s[j] = fmaf(-gr[k], bcj, s[j]);
        }
    }

    // P^T = G^{-1} A: lane li solves column li; G[i][m] via shuffle (uniform idx)
    float p[16];
    #pragma unroll
    for (int i = 0; i < 16; ++i) {
        float acc = At[i * RS_A + li];         // A[i][li]
        #pragma unroll
        for (int m = 0; m < i; ++m)
            acc = fmaf(-__shfl(gr[m], i, 16), p[m], acc);
        p[i] = acc * invd[i];
    }
    // overwrite A tile with P (row li per lane); wave-synchronous, DS pipe in-order
    {
        f4 v0 = { p[0], p[1], p[2], p[3] };
        f4 v1 = { p[4], p[5], p[6], p[7] };
        f4 v2 = { p[8], p[9], p[10], p[11] };
        f4 v3 = { p[12], p[13], p[14], p[15] };
        *(f4*)&At[li * RS_A + 0]  = v0;
        *(f4*)&At[li * RS_A + 4]  = v1;
        *(f4*)&At[li * RS_A + 8]  = v2;
        *(f4*)&At[li * RS_A + 12] = v3;
    }

    // own BBChol row (bf16 -> f32)
    float bt[16];
    {
        bh8 br0 = *(const bh8*)&Bt_[li * 16];
        bh8 br1 = *(const bh8*)&Bt_[li * 16 + 8];
        #pragma unroll
        for (int k = 0; k < 8; ++k) {
            bt[k]     = bf2f((unsigned short)br0[k]);
            bt[k + 8] = bf2f((unsigned short)br1[k]);
        }
    }

    // C = BBChol * P, row li  (read P rows broadcast)
    float cr[16];
    #pragma unroll
    for (int j = 0; j < 16; ++j) cr[j] = 0.0f;
    #pragma unroll
    for (int k = 0; k < 16; ++k) {
        f4 q0 = *(const f4*)&At[k * RS_A + 0];
        f4 q1 = *(const f4*)&At[k * RS_A + 4];
        f4 q2 = *(const f4*)&At[k * RS_A + 8];
        f4 q3 = *(const f4*)&At[k * RS_A + 12];
        float bk = bt[k];
        cr[0]  = fmaf(bk, q0[0], cr[0]);  cr[1]  = fmaf(bk, q0[1], cr[1]);
        cr[2]  = fmaf(bk, q0[2], cr[2]);  cr[3]  = fmaf(bk, q0[3], cr[3]);
        cr[4]  = fmaf(bk, q1[0], cr[4]);  cr[5]  = fmaf(bk, q1[1], cr[5]);
        cr[6]  = fmaf(bk, q1[2], cr[6]);  cr[7]  = fmaf(bk, q1[3], cr[7]);
        cr[8]  = fmaf(bk, q2[0], cr[8]);  cr[9]  = fmaf(bk, q2[1], cr[9]);
        cr[10] = fmaf(bk, q2[2], cr[10]); cr[11] = fmaf(bk, q2[3], cr[11]);
        cr[12] = fmaf(bk, q3[0], cr[12]); cr[13] = fmaf(bk, q3[1], cr[13]);
        cr[14] = fmaf(bk, q3[2], cr[14]); cr[15] = fmaf(bk, q3[3], cr[15]);
    }

    // N = -G^{-T} C^T (lane li = column li), u = G^{-T} b (replicated)
    float n_[16], uu[16];
    #pragma unroll
    for (int ii = 0; ii < 16; ++ii) {
        const int i = 15 - ii;
        float accN = -cr[i];
        float accU = ns[(size_t)t * 16 + i];
        #pragma unroll
        for (int m = i + 1; m < 16; ++m) {
            float gmi = __shfl(gr[i], m, 16);   // G[m][i]
            accN = fmaf(-gmi, n_[m], accN);
            accU = fmaf(-gmi, uu[m], accU);
        }
        n_[i] = accN * invd[i];
        uu[i] = accU * invd[i];
    }

    if (t < T_LEN - 1) {
        #pragma unroll
        for (int i = 0; i < 16; ++i)
            Nbuf[(size_t)t * 256 + i * 16 + li] = f2bf(n_[i]);   // bf16 N[t][i][j]
    }
    if (li == 0) {
        f4* U4 = (f4*)&Ubuf[(size_t)t * 16];
        f4 u0 = { uu[0], uu[1], uu[2], uu[3] };
        f4 u1 = { uu[4], uu[5], uu[6], uu[7] };
        f4 u2 = { uu[8], uu[9], uu[10], uu[11] };
        f4 u3 = { uu[12], uu[13], uu[14], uu[15] };
        U4[0] = u0; U4[1] = u1; U4[2] = u2; U4[3] = u3;
    }

    // entropy: reduce across the wave, one atomic per wave
    float esum = ent;
    #pragma unroll
    for (int off = 1; off < 64; off <<= 1)
        esum += __shfl_xor(esum, off, 64);
    if ((tid & 63) == 0) atomicAdd(entOut, -esum);
}

// ---- backward recurrence x_t = u_t + N_t x_{t+1}, overlapped chunks ----
__global__ __launch_bounds__(64, 1)
void vilds_stage2(const unsigned short* __restrict__ Nbuf, const float* __restrict__ Ubuf,
                  const float* __restrict__ PXbuf, float* __restrict__ out)
{
    const int lane = threadIdx.x;
    const int i  = lane & 15;   // output row
    const int gq = lane >> 4;   // k-quarter (4 columns each)
    const int a  = blockIdx.x * K2;
    int ts = a + K2 - 1 + W2;
    if (ts > T_LEN - 1) ts = T_LEN - 1;

    float x = Ubuf[(size_t)ts * 16 + i];   // exact at t=T-1, truncated start otherwise
    if (ts < a + K2 && gq == 0)
        out[1 + (size_t)ts * 16 + i] = x + PXbuf[(size_t)ts * 16 + i];

    ushort4 nb[PF]; float ub[PF], pxb[PF];
    #pragma unroll
    for (int q = 0; q < PF; ++q) {
        int tt = ts - 1 - q;
        if (tt >= a) {
            nb[q]  = *(const ushort4*)&Nbuf[(size_t)tt * 256 + i * 16 + gq * 4];
            ub[q]  = Ubuf[(size_t)tt * 16 + i];
            pxb[q] = PXbuf[(size_t)tt * 16 + i];
        }
    }

    for (int tb = ts - 1; tb >= a; tb -= PF) {
        #pragma unroll
        for (int q = 0; q < PF; ++q) {
            int t = tb - q;
            if (t >= a) {
                ushort4 nr = nb[q]; float ut = ub[q]; float pxt = pxb[q];
                int tp = t - PF;
                if (tp >= a) {   // prefetch PF steps ahead
                    nb[q]  = *(const ushort4*)&Nbuf[(size_t)tp * 256 + i * 16 + gq * 4];
                    ub[q]  = Ubuf[(size_t)tp * 16 + i];
                    pxb[q] = PXbuf[(size_t)tp * 16 + i];
                }
                float n0 = bf2f(nr.x), n1 = bf2f(nr.y), n2 = bf2f(nr.z), n3 = bf2f(nr.w);
                float x0 = __shfl(x, 4 * gq + 0, 16);
                float x1 = __shfl(x, 4 * gq + 1, 16);
                float x2 = __shfl(x, 4 * gq + 2, 16);
                float x3 = __shfl(x, 4 * gq + 3, 16);
                float pr = fmaf(n0, x0, n1 * x1);
                pr = fmaf(n2, x2, pr);
                pr = fmaf(n3, x3, pr);
                pr += __shfl_xor(pr, 16);
                pr += __shfl_xor(pr, 32);
                x = ut + pr;                       // x_t[i], replicated over gq
                if (t < a + K2 && gq == 0)
                    out[1 + (size_t)t * 16 + i] = x + pxt;
            }
        }
    }
}

extern "C" void kernel_launch(void* const* d_in, const int* in_sizes, int n_in,
                              void* d_out, int out_size, void* d_ws, size_t ws_size,
                              hipStream_t stream)
{
    const float* data = (const float*)d_in[0];
    const float* Wmu  = (const float*)d_in[1];
    const float* bmu  = (const float*)d_in[2];
    const float* WL   = (const float*)d_in[3];
    const float* bL   = (const float*)d_in[4];
    const float* WLx  = (const float*)d_in[5];
    const float* bLx  = (const float*)d_in[6];
    const float* ns   = (const float*)d_in[7];
    float* out = (float*)d_out;

    unsigned short* Nbuf = (unsigned short*)d_ws;                 // T*256 bf16
    float* Ubuf  = (float*)(Nbuf + (size_t)T_LEN * 256);          // T*16 f32
    float* PXbuf = Ubuf + (size_t)T_LEN * 16;                     // T*16 f32
    short* Wsw   = (short*)(PXbuf + (size_t)T_LEN * 16);          // 66*512 bf16

    hipMemsetAsync(d_out, 0, sizeof(float), stream); // zero entropy accumulator
    wswz_kernel<<<dim3(132), dim3(256), 0, stream>>>(Wmu, WL, WLx, Wsw);
    vilds_fused<<<dim3(T_LEN / 16), dim3(256), 0, stream>>>(
        data, Wsw, bmu, bL, bLx, ns, Nbuf, Ubuf, PXbuf, out);
    vilds_stage2<<<dim3(T_LEN / K2), dim3(64), 0, stream>>>(Nbuf, Ubuf, PXbuf, out);
}

// Round 4
// 470.288 us; speedup vs baseline: 1.3338x; 1.3338x over previous
//
#include <hip/hip_runtime.h>
#include <math.h>

#define T_LEN 65536

#define DROW 72      // bf16 words per staged data row (64 + 8 pad; rows 16B-aligned)
#define SLOT_A 324   // f32 words per A tile slot (16 rows x 20 + 4 pad)
#define RS_A 20      // f32 row stride inside A tile (16B-aligned rows)
#define SLOT_B 280   // bf16 words per B tile slot (16 rows x 16 + 8 pad)
#define K2 32        // stage-2 chunk length
#define W2 24        // stage-2 warm-up steps
#define PF 8         // stage-2 prefetch depth

typedef __attribute__((ext_vector_type(8))) short bh8;
typedef __attribute__((ext_vector_type(4))) float f4;

__device__ __forceinline__ unsigned short f2bf(float x) {
    union { float f; unsigned u; } v; v.f = x;
    return (unsigned short)((v.u + 0x7FFFu + ((v.u >> 16) & 1u)) >> 16);  // RNE
}
__device__ __forceinline__ float bf2f(unsigned short s) {
    union { unsigned u; float f; } v; v.u = ((unsigned)s) << 16; return v.f;
}

// ---- one-time weight swizzle into bf16 MFMA B-fragment order ----
__global__ void wswz_kernel(const float* __restrict__ Wmu, const float* __restrict__ WL,
                            const float* __restrict__ WLx, short* __restrict__ Wsw)
{
    int idx = blockIdx.x * 256 + threadIdx.x;   // 0 .. 66*512-1
    int f = idx >> 9, r = idx & 511;
    int lane = r >> 3, j = r & 7;
    int ks = f & 1, job = f >> 1;
    int k = ks * 32 + ((lane >> 4) << 3) + j;
    int n = job * 16 + (lane & 15);
    float v = (n < 16) ? Wmu[k * 16 + n]
            : (n < 272) ? WL[k * 256 + (n - 16)]
            : WLx[k * 256 + (n - 272)];
    Wsw[idx] = (short)f2bf(v);
}

// ---- fused: MFMA recognition GEMM -> LDS -> per-t factorization ----
__global__ __launch_bounds__(256, 4)
void vilds_fused(const float* __restrict__ data, const short* __restrict__ Wsw,
                 const float* __restrict__ bmu, const float* __restrict__ bL,
                 const float* __restrict__ bLx, const float* __restrict__ ns,
                 unsigned short* __restrict__ Nbuf, float* __restrict__ Ubuf,
                 float* __restrict__ PXbuf, float* __restrict__ entOut)
{
    __shared__ short Dt[17 * DROW];        // data rows t0..t0+16, bf16
    __shared__ float Atl[16 * SLOT_A];     // AAChol tiles f32 (later overwritten by P)
    __shared__ short Btl[16 * SLOT_B];     // BBChol tiles bf16

    const int tid = threadIdx.x;
    const int t0 = blockIdx.x * 16;

    // stage data rows t0..t0+16 as bf16 (row t0+16 needed for BBChol of t0+15)
    for (int idx = tid; idx < 17 * 16; idx += 256) {
        int row = idx >> 4, c4 = idx & 15;
        int tr = t0 + row;
        float4 dv = (tr < T_LEN) ? ((const float4*)data)[(size_t)tr * 16 + c4]
                                 : make_float4(0.f, 0.f, 0.f, 0.f);
        short4 b;
        b.x = (short)f2bf(dv.x); b.y = (short)f2bf(dv.y);
        b.z = (short)f2bf(dv.z); b.w = (short)f2bf(dv.w);
        *(short4*)&Dt[row * DROW + c4 * 4] = b;
    }
    __syncthreads();

    // ---- MFMA phase: jobs 0=postX, 1..16=A rows, 17..32=B rows ----
    {
        const int wv = tid >> 6, lane = tid & 63;
        const int col = lane & 15, quad = lane >> 4;
        bh8 a00 = *(const bh8*)&Dt[col * DROW + quad * 8];
        bh8 a01 = *(const bh8*)&Dt[col * DROW + quad * 8 + 32];
        bh8 a10 = *(const bh8*)&Dt[(col + 1) * DROW + quad * 8];
        bh8 a11 = *(const bh8*)&Dt[(col + 1) * DROW + quad * 8 + 32];
        for (int job = wv; job < 33; job += 4) {
            const int isB = (job >= 17);
            bh8 b0 = *(const bh8*)&Wsw[(job * 2 + 0) * 512 + lane * 8];
            bh8 b1 = *(const bh8*)&Wsw[(job * 2 + 1) * 512 + lane * 8];
            float bias;
            if (job == 0)      bias = bmu[col];
            else if (!isB)     bias = bL[(job - 1) * 16 + col] + ((col == job - 1) ? 3.0f : 0.0f);
            else               bias = bLx[(job - 17) * 16 + col];
            f4 acc = { bias, bias, bias, bias };
            acc = __builtin_amdgcn_mfma_f32_16x16x32_bf16(isB ? a10 : a00, b0, acc, 0, 0, 0);
            acc = __builtin_amdgcn_mfma_f32_16x16x32_bf16(isB ? a11 : a01, b1, acc, 0, 0, 0);
            if (job == 0) {
                #pragma unroll
                for (int r = 0; r < 4; ++r)
                    PXbuf[(size_t)(t0 + quad * 4 + r) * 16 + col] = acc[r];
            } else if (!isB) {
                int i = job - 1;
                #pragma unroll
                for (int r = 0; r < 4; ++r)
                    Atl[(quad * 4 + r) * SLOT_A + i * RS_A + col] = acc[r];
            } else {
                int i = job - 17;
                #pragma unroll
                for (int r = 0; r < 4; ++r)
                    Btl[(quad * 4 + r) * SLOT_B + i * 16 + col] = (short)f2bf(acc[r]);
            }
        }
    }
    __syncthreads();

    // ---- factorization: group gg (16 lanes, one wave) handles t = t0+gg ----
    const int gg = tid >> 4, li = tid & 15;
    const int t = t0 + gg;
    float* At = &Atl[gg * SLOT_A];
    const short* Bt_ = &Btl[gg * SLOT_B];

    // own A row
    float a[16];
    #pragma unroll
    for (int c = 0; c < 4; ++c) {
        f4 v = *(const f4*)&At[li * RS_A + c * 4];
        a[4*c+0] = v[0]; a[4*c+1] = v[1]; a[4*c+2] = v[2]; a[4*c+3] = v[3];
    }

    // S = A A^T + 1e-6 I, row li
    float s[16];
    #pragma unroll
    for (int j = 0; j < 16; ++j) {
        f4 r0 = *(const f4*)&At[j * RS_A + 0];
        f4 r1 = *(const f4*)&At[j * RS_A + 4];
        f4 r2 = *(const f4*)&At[j * RS_A + 8];
        f4 r3 = *(const f4*)&At[j * RS_A + 12];
        float acc = (j == li) ? 1e-6f : 0.0f;
        acc = fmaf(a[0], r0[0], acc);  acc = fmaf(a[1], r0[1], acc);
        acc = fmaf(a[2], r0[2], acc);  acc = fmaf(a[3], r0[3], acc);
        acc = fmaf(a[4], r1[0], acc);  acc = fmaf(a[5], r1[1], acc);
        acc = fmaf(a[6], r1[2], acc);  acc = fmaf(a[7], r1[3], acc);
        acc = fmaf(a[8], r2[0], acc);  acc = fmaf(a[9], r2[1], acc);
        acc = fmaf(a[10], r2[2], acc); acc = fmaf(a[11], r2[3], acc);
        acc = fmaf(a[12], r3[0], acc); acc = fmaf(a[13], r3[1], acc);
        acc = fmaf(a[14], r3[2], acc); acc = fmaf(a[15], r3[3], acc);
        s[j] = acc;
    }

    // Cholesky G of S (lane li owns row li), shuffle-based
    float gr[16], invd[16];
    float ent = 0.0f;
    #pragma unroll
    for (int k = 0; k < 16; ++k) {
        float dkk = __shfl(s[k], k, 16);
        dkk = fmaxf(dkk, 1e-20f);
        if (li == k) ent += 0.5f * logf(dkk);
        float inv = 1.0f / sqrtf(dkk);
        invd[k] = inv;
        gr[k] = s[k] * inv;                    // G[li][k], valid li>=k
        #pragma unroll
        for (int j = k + 1; j < 16; ++j) {
            float bcj = __shfl(gr[k], j, 16);  // G[j][k]
            s[j] = fmaf(-gr[k], bcj, s[j]);
        }
    }

    // P^T = G^{-1} A: lane li solves column li
    float p[16];
    #pragma unroll
    for (int i = 0; i < 16; ++i) {
        float acc = At[i * RS_A + li];         // A[i][li]
        #pragma unroll
        for (int m = 0; m < i; ++m)
            acc = fmaf(-__shfl(gr[m], i, 16), p[m], acc);
        p[i] = acc * invd[i];
    }
    // overwrite A tile with P (row li per lane); wave-synchronous
    {
        f4 v0 = { p[0], p[1], p[2], p[3] };
        f4 v1 = { p[4], p[5], p[6], p[7] };
        f4 v2 = { p[8], p[9], p[10], p[11] };
        f4 v3 = { p[12], p[13], p[14], p[15] };
        *(f4*)&At[li * RS_A + 0]  = v0;
        *(f4*)&At[li * RS_A + 4]  = v1;
        *(f4*)&At[li * RS_A + 8]  = v2;
        *(f4*)&At[li * RS_A + 12] = v3;
    }

    // own BBChol row (bf16 -> f32)
    float bt[16];
    {
        bh8 br0 = *(const bh8*)&Bt_[li * 16];
        bh8 br1 = *(const bh8*)&Bt_[li * 16 + 8];
        #pragma unroll
        for (int k = 0; k < 8; ++k) {
            bt[k]     = bf2f((unsigned short)br0[k]);
            bt[k + 8] = bf2f((unsigned short)br1[k]);
        }
    }

    // C = BBChol * P, row li  (read P rows broadcast)
    float cr[16];
    #pragma unroll
    for (int j = 0; j < 16; ++j) cr[j] = 0.0f;
    #pragma unroll
    for (int k = 0; k < 16; ++k) {
        f4 q0 = *(const f4*)&At[k * RS_A + 0];
        f4 q1 = *(const f4*)&At[k * RS_A + 4];
        f4 q2 = *(const f4*)&At[k * RS_A + 8];
        f4 q3 = *(const f4*)&At[k * RS_A + 12];
        float bk = bt[k];
        cr[0]  = fmaf(bk, q0[0], cr[0]);  cr[1]  = fmaf(bk, q0[1], cr[1]);
        cr[2]  = fmaf(bk, q0[2], cr[2]);  cr[3]  = fmaf(bk, q0[3], cr[3]);
        cr[4]  = fmaf(bk, q1[0], cr[4]);  cr[5]  = fmaf(bk, q1[1], cr[5]);
        cr[6]  = fmaf(bk, q1[2], cr[6]);  cr[7]  = fmaf(bk, q1[3], cr[7]);
        cr[8]  = fmaf(bk, q2[0], cr[8]);  cr[9]  = fmaf(bk, q2[1], cr[9]);
        cr[10] = fmaf(bk, q2[2], cr[10]); cr[11] = fmaf(bk, q2[3], cr[11]);
        cr[12] = fmaf(bk, q3[0], cr[12]); cr[13] = fmaf(bk, q3[1], cr[13]);
        cr[14] = fmaf(bk, q3[2], cr[14]); cr[15] = fmaf(bk, q3[3], cr[15]);
    }

    // N = -G^{-T} C^T (lane li = column li), u = G^{-T} b (replicated)
    float n_[16], uu[16];
    #pragma unroll
    for (int ii = 0; ii < 16; ++ii) {
        const int i = 15 - ii;
        float accN = -cr[i];
        float accU = ns[(size_t)t * 16 + i];
        #pragma unroll
        for (int m = i + 1; m < 16; ++m) {
            float gmi = __shfl(gr[i], m, 16);   // G[m][i]
            accN = fmaf(-gmi, n_[m], accN);
            accU = fmaf(-gmi, uu[m], accU);
        }
        n_[i] = accN * invd[i];
        uu[i] = accU * invd[i];
    }

    if (t < T_LEN - 1) {
        #pragma unroll
        for (int i = 0; i < 16; ++i)
            Nbuf[(size_t)t * 256 + i * 16 + li] = f2bf(n_[i]);   // bf16 N[t][i][j]
    }
    if (li == 0) {
        f4* U4 = (f4*)&Ubuf[(size_t)t * 16];
        f4 u0 = { uu[0], uu[1], uu[2], uu[3] };
        f4 u1 = { uu[4], uu[5], uu[6], uu[7] };
        f4 u2 = { uu[8], uu[9], uu[10], uu[11] };
        f4 u3 = { uu[12], uu[13], uu[14], uu[15] };
        U4[0] = u0; U4[1] = u1; U4[2] = u2; U4[3] = u3;
    }

    // entropy: reduce across the wave, one atomic per wave
    float esum = ent;
    #pragma unroll
    for (int off = 1; off < 64; off <<= 1)
        esum += __shfl_xor(esum, off, 64);
    if ((tid & 63) == 0) atomicAdd(entOut, -esum);
}

// ---- backward recurrence x_t = u_t + N_t x_{t+1}, overlapped chunks ----
__global__ __launch_bounds__(64, 1)
void vilds_stage2(const unsigned short* __restrict__ Nbuf, const float* __restrict__ Ubuf,
                  const float* __restrict__ PXbuf, float* __restrict__ out)
{
    const int lane = threadIdx.x;
    const int i  = lane & 15;   // output row
    const int gq = lane >> 4;   // k-quarter (4 columns each)
    const int a  = blockIdx.x * K2;
    int ts = a + K2 - 1 + W2;
    if (ts > T_LEN - 1) ts = T_LEN - 1;

    float x = Ubuf[(size_t)ts * 16 + i];   // exact at t=T-1, truncated start otherwise
    if (ts < a + K2 && gq == 0)
        out[1 + (size_t)ts * 16 + i] = x + PXbuf[(size_t)ts * 16 + i];

    ushort4 nb[PF]; float ub[PF], pxb[PF];
    #pragma unroll
    for (int q = 0; q < PF; ++q) {
        int tt = ts - 1 - q;
        if (tt >= a) {
            nb[q]  = *(const ushort4*)&Nbuf[(size_t)tt * 256 + i * 16 + gq * 4];
            ub[q]  = Ubuf[(size_t)tt * 16 + i];
            pxb[q] = PXbuf[(size_t)tt * 16 + i];
        }
    }

    for (int tb = ts - 1; tb >= a; tb -= PF) {
        #pragma unroll
        for (int q = 0; q < PF; ++q) {
            int t = tb - q;
            if (t >= a) {
                ushort4 nr = nb[q]; float ut = ub[q]; float pxt = pxb[q];
                int tp = t - PF;
                if (tp >= a) {   // prefetch PF steps ahead
                    nb[q]  = *(const ushort4*)&Nbuf[(size_t)tp * 256 + i * 16 + gq * 4];
                    ub[q]  = Ubuf[(size_t)tp * 16 + i];
                    pxb[q] = PXbuf[(size_t)tp * 16 + i];
                }
                float n0 = bf2f(nr.x), n1 = bf2f(nr.y), n2 = bf2f(nr.z), n3 = bf2f(nr.w);
                float x0 = __shfl(x, 4 * gq + 0, 16);
                float x1 = __shfl(x, 4 * gq + 1, 16);
                float x2 = __shfl(x, 4 * gq + 2, 16);
                float x3 = __shfl(x, 4 * gq + 3, 16);
                float pr = fmaf(n0, x0, n1 * x1);
                pr = fmaf(n2, x2, pr);
                pr = fmaf(n3, x3, pr);
                pr += __shfl_xor(pr, 16);
                pr += __shfl_xor(pr, 32);
                x = ut + pr;                       // x_t[i], replicated over gq
                if (t < a + K2 && gq == 0)
                    out[1 + (size_t)t * 16 + i] = x + pxt;
            }
        }
    }
}

extern "C" void kernel_launch(void* const* d_in, const int* in_sizes, int n_in,
                              void* d_out, int out_size, void* d_ws, size_t ws_size,
                              hipStream_t stream)
{
    const float* data = (const float*)d_in[0];
    const float* Wmu  = (const float*)d_in[1];
    const float* bmu  = (const float*)d_in[2];
    const float* WL   = (const float*)d_in[3];
    const float* bL   = (const float*)d_in[4];
    const float* WLx  = (const float*)d_in[5];
    const float* bLx  = (const float*)d_in[6];
    const float* ns   = (const float*)d_in[7];
    float* out = (float*)d_out;

    unsigned short* Nbuf = (unsigned short*)d_ws;                 // T*256 bf16
    float* Ubuf  = (float*)(Nbuf + (size_t)T_LEN * 256);          // T*16 f32
    float* PXbuf = Ubuf + (size_t)T_LEN * 16;                     // T*16 f32
    short* Wsw   = (short*)(PXbuf + (size_t)T_LEN * 16);          // 66*512 bf16

    hipMemsetAsync(d_out, 0, sizeof(float), stream); // zero entropy accumulator
    wswz_kernel<<<dim3(132), dim3(256), 0, stream>>>(Wmu, WL, WLx, Wsw);
    vilds_fused<<<dim3(T_LEN / 16), dim3(256), 0, stream>>>(
        data, Wsw, bmu, bL, bLx, ns, Nbuf, Ubuf, PXbuf, out);
    vilds_stage2<<<dim3(T_LEN / K2), dim3(64), 0, stream>>>(Nbuf, Ubuf, PXbuf, out);
}

// Round 5
// 334.171 us; speedup vs baseline: 1.8771x; 1.4073x over previous
//
#include <hip/hip_runtime.h>
#include <math.h>

#define T_LEN 65536

#define DROW 72      // bf16 words per staged data row (64 + 8 pad; rows 16B-aligned)
#define SLOT_A 324   // f32 words per A tile slot (16 rows x 20 + 4 pad)
#define RS_A 20      // f32 row stride inside A tile (16B-aligned rows)
#define SLOT_B 280   // bf16 words per B tile slot (16 rows x 16 + 8 pad)
#define K2 32        // stage-2 chunk length
#define W2 24        // stage-2 warm-up steps
#define PF 8         // stage-2 prefetch depth

typedef __attribute__((ext_vector_type(8))) short bh8;
typedef __attribute__((ext_vector_type(4))) float f4;

__device__ __forceinline__ unsigned short f2bf(float x) {
    union { float f; unsigned u; } v; v.f = x;
    return (unsigned short)((v.u + 0x7FFFu + ((v.u >> 16) & 1u)) >> 16);  // RNE
}
__device__ __forceinline__ float bf2f(unsigned short s) {
    union { unsigned u; float f; } v; v.u = ((unsigned)s) << 16; return v.f;
}

// ---- one-time weight swizzle into bf16 MFMA B-fragment order ----
__global__ void wswz_kernel(const float* __restrict__ Wmu, const float* __restrict__ WL,
                            const float* __restrict__ WLx, short* __restrict__ Wsw)
{
    int idx = blockIdx.x * 256 + threadIdx.x;   // 0 .. 66*512-1
    int f = idx >> 9, r = idx & 511;
    int lane = r >> 3, j = r & 7;
    int ks = f & 1, job = f >> 1;
    int k = ks * 32 + ((lane >> 4) << 3) + j;
    int n = job * 16 + (lane & 15);
    float v = (n < 16) ? Wmu[k * 16 + n]
            : (n < 272) ? WL[k * 256 + (n - 16)]
            : WLx[k * 256 + (n - 272)];
    Wsw[idx] = (short)f2bf(v);
}

// ---- fused: MFMA recognition GEMM -> LDS -> per-t factorization ----
// launch_bounds(256,2): 256-VGPR ceiling. The factorization phase holds ~75
// live floats/lane; capping below ~110 VGPRs causes scratch spills whose
// dirty-line evictions dominated R3/R4 (WRITE_SIZE 0.5-0.7 GB).
__global__ __launch_bounds__(256, 2)
void vilds_fused(const float* __restrict__ data, const short* __restrict__ Wsw,
                 const float* __restrict__ bmu, const float* __restrict__ bL,
                 const float* __restrict__ bLx, const float* __restrict__ ns,
                 unsigned short* __restrict__ Nbuf, float* __restrict__ Ubuf,
                 float* __restrict__ PXbuf, float* __restrict__ entOut)
{
    __shared__ short Dt[17 * DROW];        // data rows t0..t0+16, bf16
    __shared__ float Atl[16 * SLOT_A];     // AAChol tiles f32 (later overwritten by P)
    __shared__ short Btl[16 * SLOT_B];     // BBChol tiles bf16

    const int tid = threadIdx.x;
    const int t0 = blockIdx.x * 16;

    // stage data rows t0..t0+16 as bf16 (row t0+16 needed for BBChol of t0+15)
    for (int idx = tid; idx < 17 * 16; idx += 256) {
        int row = idx >> 4, c4 = idx & 15;
        int tr = t0 + row;
        float4 dv = (tr < T_LEN) ? ((const float4*)data)[(size_t)tr * 16 + c4]
                                 : make_float4(0.f, 0.f, 0.f, 0.f);
        short4 b;
        b.x = (short)f2bf(dv.x); b.y = (short)f2bf(dv.y);
        b.z = (short)f2bf(dv.z); b.w = (short)f2bf(dv.w);
        *(short4*)&Dt[row * DROW + c4 * 4] = b;
    }
    __syncthreads();

    // ---- MFMA phase: jobs 0=postX, 1..16=A rows, 17..32=B rows ----
    {
        const int wv = tid >> 6, lane = tid & 63;
        const int col = lane & 15, quad = lane >> 4;
        bh8 a00 = *(const bh8*)&Dt[col * DROW + quad * 8];
        bh8 a01 = *(const bh8*)&Dt[col * DROW + quad * 8 + 32];
        bh8 a10 = *(const bh8*)&Dt[(col + 1) * DROW + quad * 8];
        bh8 a11 = *(const bh8*)&Dt[(col + 1) * DROW + quad * 8 + 32];
        for (int job = wv; job < 33; job += 4) {
            const int isB = (job >= 17);
            bh8 b0 = *(const bh8*)&Wsw[(job * 2 + 0) * 512 + lane * 8];
            bh8 b1 = *(const bh8*)&Wsw[(job * 2 + 1) * 512 + lane * 8];
            float bias;
            if (job == 0)      bias = bmu[col];
            else if (!isB)     bias = bL[(job - 1) * 16 + col] + ((col == job - 1) ? 3.0f : 0.0f);
            else               bias = bLx[(job - 17) * 16 + col];
            f4 acc = { bias, bias, bias, bias };
            acc = __builtin_amdgcn_mfma_f32_16x16x32_bf16(isB ? a10 : a00, b0, acc, 0, 0, 0);
            acc = __builtin_amdgcn_mfma_f32_16x16x32_bf16(isB ? a11 : a01, b1, acc, 0, 0, 0);
            if (job == 0) {
                #pragma unroll
                for (int r = 0; r < 4; ++r)
                    PXbuf[(size_t)(t0 + quad * 4 + r) * 16 + col] = acc[r];
            } else if (!isB) {
                int i = job - 1;
                #pragma unroll
                for (int r = 0; r < 4; ++r)
                    Atl[(quad * 4 + r) * SLOT_A + i * RS_A + col] = acc[r];
            } else {
                int i = job - 17;
                #pragma unroll
                for (int r = 0; r < 4; ++r)
                    Btl[(quad * 4 + r) * SLOT_B + i * 16 + col] = (short)f2bf(acc[r]);
            }
        }
    }
    __syncthreads();

    // ---- factorization: group gg (16 lanes, one wave) handles t = t0+gg ----
    const int gg = tid >> 4, li = tid & 15;
    const int t = t0 + gg;
    float* At = &Atl[gg * SLOT_A];
    const short* Bt_ = &Btl[gg * SLOT_B];

    // S = A A^T + 1e-6 I, row li (own A row in a[], dead after this block)
    float s[16];
    {
        float a[16];
        #pragma unroll
        for (int c = 0; c < 4; ++c) {
            f4 v = *(const f4*)&At[li * RS_A + c * 4];
            a[4*c+0] = v[0]; a[4*c+1] = v[1]; a[4*c+2] = v[2]; a[4*c+3] = v[3];
        }
        #pragma unroll
        for (int j = 0; j < 16; ++j) {
            f4 r0 = *(const f4*)&At[j * RS_A + 0];
            f4 r1 = *(const f4*)&At[j * RS_A + 4];
            f4 r2 = *(const f4*)&At[j * RS_A + 8];
            f4 r3 = *(const f4*)&At[j * RS_A + 12];
            float acc = (j == li) ? 1e-6f : 0.0f;
            acc = fmaf(a[0], r0[0], acc);  acc = fmaf(a[1], r0[1], acc);
            acc = fmaf(a[2], r0[2], acc);  acc = fmaf(a[3], r0[3], acc);
            acc = fmaf(a[4], r1[0], acc);  acc = fmaf(a[5], r1[1], acc);
            acc = fmaf(a[6], r1[2], acc);  acc = fmaf(a[7], r1[3], acc);
            acc = fmaf(a[8], r2[0], acc);  acc = fmaf(a[9], r2[1], acc);
            acc = fmaf(a[10], r2[2], acc); acc = fmaf(a[11], r2[3], acc);
            acc = fmaf(a[12], r3[0], acc); acc = fmaf(a[13], r3[1], acc);
            acc = fmaf(a[14], r3[2], acc); acc = fmaf(a[15], r3[3], acc);
            s[j] = acc;
        }
    }

    // Cholesky of S in place: s[] becomes G row li (valid lower triangle).
    // own_inv = 1/G[li][li]; invd[k] is recovered by uniform shuffle.
    float own_inv = 0.0f, ent = 0.0f;
    #pragma unroll
    for (int k = 0; k < 16; ++k) {
        float dkk = __shfl(s[k], k, 16);
        dkk = fmaxf(dkk, 1e-20f);
        float inv = rsqrtf(dkk);
        if (li == k) { own_inv = inv; ent = 0.5f * __logf(dkk); }
        s[k] *= inv;                            // G[li][k], valid li>=k
        #pragma unroll
        for (int j = k + 1; j < 16; ++j) {
            float gjk = __shfl(s[k], j, 16);    // G[j][k]
            s[j] = fmaf(-s[k], gjk, s[j]);
        }
    }

    // P^T = G^{-1} A: lane li solves column li; G[i][m] = shfl(s[m], i)
    {
        float p[16];
        #pragma unroll
        for (int i = 0; i < 16; ++i) {
            float acc = At[i * RS_A + li];       // A[i][li]
            #pragma unroll
            for (int m = 0; m < i; ++m)
                acc = fmaf(-__shfl(s[m], i, 16), p[m], acc);
            p[i] = acc * __shfl(own_inv, i, 16);
        }
        // overwrite A tile with P (row li per lane); wave-synchronous
        f4 v0 = { p[0], p[1], p[2], p[3] };
        f4 v1 = { p[4], p[5], p[6], p[7] };
        f4 v2 = { p[8], p[9], p[10], p[11] };
        f4 v3 = { p[12], p[13], p[14], p[15] };
        *(f4*)&At[li * RS_A + 0]  = v0;
        *(f4*)&At[li * RS_A + 4]  = v1;
        *(f4*)&At[li * RS_A + 8]  = v2;
        *(f4*)&At[li * RS_A + 12] = v3;
    }

    // C = BBChol * P, row li (bt dead after this block)
    float cr[16];
    {
        float bt[16];
        bh8 br0 = *(const bh8*)&Bt_[li * 16];
        bh8 br1 = *(const bh8*)&Bt_[li * 16 + 8];
        #pragma unroll
        for (int k = 0; k < 8; ++k) {
            bt[k]     = bf2f((unsigned short)br0[k]);
            bt[k + 8] = bf2f((unsigned short)br1[k]);
        }
        #pragma unroll
        for (int j = 0; j < 16; ++j) cr[j] = 0.0f;
        #pragma unroll
        for (int k = 0; k < 16; ++k) {
            f4 q0 = *(const f4*)&At[k * RS_A + 0];
            f4 q1 = *(const f4*)&At[k * RS_A + 4];
            f4 q2 = *(const f4*)&At[k * RS_A + 8];
            f4 q3 = *(const f4*)&At[k * RS_A + 12];
            float bk = bt[k];
            cr[0]  = fmaf(bk, q0[0], cr[0]);  cr[1]  = fmaf(bk, q0[1], cr[1]);
            cr[2]  = fmaf(bk, q0[2], cr[2]);  cr[3]  = fmaf(bk, q0[3], cr[3]);
            cr[4]  = fmaf(bk, q1[0], cr[4]);  cr[5]  = fmaf(bk, q1[1], cr[5]);
            cr[6]  = fmaf(bk, q1[2], cr[6]);  cr[7]  = fmaf(bk, q1[3], cr[7]);
            cr[8]  = fmaf(bk, q2[0], cr[8]);  cr[9]  = fmaf(bk, q2[1], cr[9]);
            cr[10] = fmaf(bk, q2[2], cr[10]); cr[11] = fmaf(bk, q2[3], cr[11]);
            cr[12] = fmaf(bk, q3[0], cr[12]); cr[13] = fmaf(bk, q3[1], cr[13]);
            cr[14] = fmaf(bk, q3[2], cr[14]); cr[15] = fmaf(bk, q3[3], cr[15]);
        }
    }

    // N = -G^{-T} C^T (lane li = column li), u = G^{-T} b (replicated)
    // G[m][i] = shfl(s[i], m); invd[i] = shfl(own_inv, i)
    float n_[16], uu[16];
    #pragma unroll
    for (int ii = 0; ii < 16; ++ii) {
        const int i = 15 - ii;
        float accN = -cr[i];
        float accU = ns[(size_t)t * 16 + i];
        #pragma unroll
        for (int m = i + 1; m < 16; ++m) {
            float gmi = __shfl(s[i], m, 16);
            accN = fmaf(-gmi, n_[m], accN);
            accU = fmaf(-gmi, uu[m], accU);
        }
        float inv_i = __shfl(own_inv, i, 16);
        n_[i] = accN * inv_i;
        uu[i] = accU * inv_i;
    }

    if (t < T_LEN - 1) {
        #pragma unroll
        for (int i = 0; i < 16; ++i)
            Nbuf[(size_t)t * 256 + i * 16 + li] = f2bf(n_[i]);   // bf16 N[t][i][j]
    }
    if (li == 0) {
        f4* U4 = (f4*)&Ubuf[(size_t)t * 16];
        f4 u0 = { uu[0], uu[1], uu[2], uu[3] };
        f4 u1 = { uu[4], uu[5], uu[6], uu[7] };
        f4 u2 = { uu[8], uu[9], uu[10], uu[11] };
        f4 u3 = { uu[12], uu[13], uu[14], uu[15] };
        U4[0] = u0; U4[1] = u1; U4[2] = u2; U4[3] = u3;
    }

    // entropy: reduce across the wave, one atomic per wave
    float esum = ent;
    #pragma unroll
    for (int off = 1; off < 64; off <<= 1)
        esum += __shfl_xor(esum, off, 64);
    if ((tid & 63) == 0) atomicAdd(entOut, -esum);
}

// ---- backward recurrence x_t = u_t + N_t x_{t+1}, overlapped chunks ----
__global__ __launch_bounds__(64, 1)
void vilds_stage2(const unsigned short* __restrict__ Nbuf, const float* __restrict__ Ubuf,
                  const float* __restrict__ PXbuf, float* __restrict__ out)
{
    const int lane = threadIdx.x;
    const int i  = lane & 15;   // output row
    const int gq = lane >> 4;   // k-quarter (4 columns each)
    const int a  = blockIdx.x * K2;
    int ts = a + K2 - 1 + W2;
    if (ts > T_LEN - 1) ts = T_LEN - 1;

    float x = Ubuf[(size_t)ts * 16 + i];   // exact at t=T-1, truncated start otherwise
    if (ts < a + K2 && gq == 0)
        out[1 + (size_t)ts * 16 + i] = x + PXbuf[(size_t)ts * 16 + i];

    ushort4 nb[PF]; float ub[PF], pxb[PF];
    #pragma unroll
    for (int q = 0; q < PF; ++q) {
        int tt = ts - 1 - q;
        if (tt >= a) {
            nb[q]  = *(const ushort4*)&Nbuf[(size_t)tt * 256 + i * 16 + gq * 4];
            ub[q]  = Ubuf[(size_t)tt * 16 + i];
            pxb[q] = PXbuf[(size_t)tt * 16 + i];
        }
    }

    for (int tb = ts - 1; tb >= a; tb -= PF) {
        #pragma unroll
        for (int q = 0; q < PF; ++q) {
            int t = tb - q;
            if (t >= a) {
                ushort4 nr = nb[q]; float ut = ub[q]; float pxt = pxb[q];
                int tp = t - PF;
                if (tp >= a) {   // prefetch PF steps ahead
                    nb[q]  = *(const ushort4*)&Nbuf[(size_t)tp * 256 + i * 16 + gq * 4];
                    ub[q]  = Ubuf[(size_t)tp * 16 + i];
                    pxb[q] = PXbuf[(size_t)tp * 16 + i];
                }
                float n0 = bf2f(nr.x), n1 = bf2f(nr.y), n2 = bf2f(nr.z), n3 = bf2f(nr.w);
                float x0 = __shfl(x, 4 * gq + 0, 16);
                float x1 = __shfl(x, 4 * gq + 1, 16);
                float x2 = __shfl(x, 4 * gq + 2, 16);
                float x3 = __shfl(x, 4 * gq + 3, 16);
                float pr = fmaf(n0, x0, n1 * x1);
                pr = fmaf(n2, x2, pr);
                pr = fmaf(n3, x3, pr);
                pr += __shfl_xor(pr, 16);
                pr += __shfl_xor(pr, 32);
                x = ut + pr;                       // x_t[i], replicated over gq
                if (t < a + K2 && gq == 0)
                    out[1 + (size_t)t * 16 + i] = x + pxt;
            }
        }
    }
}

extern "C" void kernel_launch(void* const* d_in, const int* in_sizes, int n_in,
                              void* d_out, int out_size, void* d_ws, size_t ws_size,
                              hipStream_t stream)
{
    const float* data = (const float*)d_in[0];
    const float* Wmu  = (const float*)d_in[1];
    const float* bmu  = (const float*)d_in[2];
    const float* WL   = (const float*)d_in[3];
    const float* bL   = (const float*)d_in[4];
    const float* WLx  = (const float*)d_in[5];
    const float* bLx  = (const float*)d_in[6];
    const float* ns   = (const float*)d_in[7];
    float* out = (float*)d_out;

    unsigned short* Nbuf = (unsigned short*)d_ws;                 // T*256 bf16
    float* Ubuf  = (float*)(Nbuf + (size_t)T_LEN * 256);          // T*16 f32
    float* PXbuf = Ubuf + (size_t)T_LEN * 16;                     // T*16 f32
    short* Wsw   = (short*)(PXbuf + (size_t)T_LEN * 16);          // 66*512 bf16

    hipMemsetAsync(d_out, 0, sizeof(float), stream); // zero entropy accumulator
    wswz_kernel<<<dim3(132), dim3(256), 0, stream>>>(Wmu, WL, WLx, Wsw);
    vilds_fused<<<dim3(T_LEN / 16), dim3(256), 0, stream>>>(
        data, Wsw, bmu, bL, bLx, ns, Nbuf, Ubuf, PXbuf, out);
    vilds_stage2<<<dim3(T_LEN / K2), dim3(64), 0, stream>>>(Nbuf, Ubuf, PXbuf, out);
}

// Round 6
// 330.174 us; speedup vs baseline: 1.8998x; 1.0121x over previous
//
#include <hip/hip_runtime.h>
#include <math.h>

#define T_LEN 65536

#define DROW 72      // bf16 words per staged data row (64 + 8 pad; rows 16B-aligned)
#define SLOT_A 324   // f32 words per A tile slot (16 rows x 20 + 4 pad)
#define RS_A 20      // f32 row stride inside A tile (16B-aligned rows)
#define SLOT_B 280   // bf16 words per B tile slot (16 rows x 16 + 8 pad)
#define GCS 264      // f32 words per G-column slot (16 cols x 16 + 8 pad)
#define K2 32        // stage-2 chunk length
#define W2 24        // stage-2 warm-up steps
#define PF 8         // stage-2 prefetch depth

typedef __attribute__((ext_vector_type(8))) short bh8;
typedef __attribute__((ext_vector_type(4))) float f4;

__device__ __forceinline__ unsigned short f2bf(float x) {
    union { float f; unsigned u; } v; v.f = x;
    return (unsigned short)((v.u + 0x7FFFu + ((v.u >> 16) & 1u)) >> 16);  // RNE
}
__device__ __forceinline__ float bf2f(unsigned short s) {
    union { unsigned u; float f; } v; v.u = ((unsigned)s) << 16; return v.f;
}

// ---- one-time weight swizzle into bf16 MFMA B-fragment order ----
__global__ void wswz_kernel(const float* __restrict__ Wmu, const float* __restrict__ WL,
                            const float* __restrict__ WLx, short* __restrict__ Wsw)
{
    int idx = blockIdx.x * 256 + threadIdx.x;   // 0 .. 66*512-1
    int f = idx >> 9, r = idx & 511;
    int lane = r >> 3, j = r & 7;
    int ks = f & 1, job = f >> 1;
    int k = ks * 32 + ((lane >> 4) << 3) + j;
    int n = job * 16 + (lane & 15);
    float v = (n < 16) ? Wmu[k * 16 + n]
            : (n < 272) ? WL[k * 256 + (n - 16)]
            : WLx[k * 256 + (n - 272)];
    Wsw[idx] = (short)f2bf(v);
}

// ---- fused: MFMA recognition GEMM -> LDS -> per-t factorization ----
// Shuffle-free factorization: G is staged by COLUMNS in LDS (Gcol[k][j]=G[j][k]).
// All cross-lane traffic is broadcast ds_read_b128 (prefetchable, no bpermute).
__global__ __launch_bounds__(256, 2)
void vilds_fused(const float* __restrict__ data, const short* __restrict__ Wsw,
                 const float* __restrict__ bmu, const float* __restrict__ bL,
                 const float* __restrict__ bLx, const float* __restrict__ ns,
                 unsigned short* __restrict__ Nbuf, float* __restrict__ Ubuf,
                 float* __restrict__ PXbuf, float* __restrict__ entOut)
{
    __shared__ short Dt[17 * DROW];        // data rows t0..t0+16, bf16
    __shared__ float Atl[16 * SLOT_A];     // AAChol tiles f32 (later overwritten by P^T)
    __shared__ short Btl[16 * SLOT_B];     // BBChol tiles bf16
    __shared__ float Gcol[16 * GCS];       // G stored by columns, per group

    const int tid = threadIdx.x;
    const int t0 = blockIdx.x * 16;

    // stage data rows t0..t0+16 as bf16 (row t0+16 needed for BBChol of t0+15)
    for (int idx = tid; idx < 17 * 16; idx += 256) {
        int row = idx >> 4, c4 = idx & 15;
        int tr = t0 + row;
        float4 dv = (tr < T_LEN) ? ((const float4*)data)[(size_t)tr * 16 + c4]
                                 : make_float4(0.f, 0.f, 0.f, 0.f);
        short4 b;
        b.x = (short)f2bf(dv.x); b.y = (short)f2bf(dv.y);
        b.z = (short)f2bf(dv.z); b.w = (short)f2bf(dv.w);
        *(short4*)&Dt[row * DROW + c4 * 4] = b;
    }
    __syncthreads();

    // ---- MFMA phase: jobs 0=postX, 1..16=A rows, 17..32=B rows ----
    {
        const int wv = tid >> 6, lane = tid & 63;
        const int col = lane & 15, quad = lane >> 4;
        bh8 a00 = *(const bh8*)&Dt[col * DROW + quad * 8];
        bh8 a01 = *(const bh8*)&Dt[col * DROW + quad * 8 + 32];
        bh8 a10 = *(const bh8*)&Dt[(col + 1) * DROW + quad * 8];
        bh8 a11 = *(const bh8*)&Dt[(col + 1) * DROW + quad * 8 + 32];
        for (int job = wv; job < 33; job += 4) {
            const int isB = (job >= 17);
            bh8 b0 = *(const bh8*)&Wsw[(job * 2 + 0) * 512 + lane * 8];
            bh8 b1 = *(const bh8*)&Wsw[(job * 2 + 1) * 512 + lane * 8];
            float bias;
            if (job == 0)      bias = bmu[col];
            else if (!isB)     bias = bL[(job - 1) * 16 + col] + ((col == job - 1) ? 3.0f : 0.0f);
            else               bias = bLx[(job - 17) * 16 + col];
            f4 acc = { bias, bias, bias, bias };
            acc = __builtin_amdgcn_mfma_f32_16x16x32_bf16(isB ? a10 : a00, b0, acc, 0, 0, 0);
            acc = __builtin_amdgcn_mfma_f32_16x16x32_bf16(isB ? a11 : a01, b1, acc, 0, 0, 0);
            if (job == 0) {
                #pragma unroll
                for (int r = 0; r < 4; ++r)
                    PXbuf[(size_t)(t0 + quad * 4 + r) * 16 + col] = acc[r];
            } else if (!isB) {
                int i = job - 1;
                #pragma unroll
                for (int r = 0; r < 4; ++r)
                    Atl[(quad * 4 + r) * SLOT_A + i * RS_A + col] = acc[r];
            } else {
                int i = job - 17;
                #pragma unroll
                for (int r = 0; r < 4; ++r)
                    Btl[(quad * 4 + r) * SLOT_B + i * 16 + col] = (short)f2bf(acc[r]);
            }
        }
    }
    __syncthreads();

    // ---- factorization: group gg (16 lanes, one wave) handles t = t0+gg ----
    const int gg = tid >> 4, li = tid & 15;
    const int t = t0 + gg;
    float* At = &Atl[gg * SLOT_A];
    const short* Bt_ = &Btl[gg * SLOT_B];
    float* Gc = &Gcol[gg * GCS];

    // S = A A^T + 1e-6 I, row li (own A row in a[], dead after this block)
    float s[16];
    {
        float a[16];
        #pragma unroll
        for (int c = 0; c < 4; ++c) {
            f4 v = *(const f4*)&At[li * RS_A + c * 4];
            a[4*c+0] = v[0]; a[4*c+1] = v[1]; a[4*c+2] = v[2]; a[4*c+3] = v[3];
        }
        #pragma unroll
        for (int j = 0; j < 16; ++j) {
            f4 r0 = *(const f4*)&At[j * RS_A + 0];
            f4 r1 = *(const f4*)&At[j * RS_A + 4];
            f4 r2 = *(const f4*)&At[j * RS_A + 8];
            f4 r3 = *(const f4*)&At[j * RS_A + 12];
            float acc = (j == li) ? 1e-6f : 0.0f;
            acc = fmaf(a[0], r0[0], acc);  acc = fmaf(a[1], r0[1], acc);
            acc = fmaf(a[2], r0[2], acc);  acc = fmaf(a[3], r0[3], acc);
            acc = fmaf(a[4], r1[0], acc);  acc = fmaf(a[5], r1[1], acc);
            acc = fmaf(a[6], r1[2], acc);  acc = fmaf(a[7], r1[3], acc);
            acc = fmaf(a[8], r2[0], acc);  acc = fmaf(a[9], r2[1], acc);
            acc = fmaf(a[10], r2[2], acc); acc = fmaf(a[11], r2[3], acc);
            acc = fmaf(a[12], r3[0], acc); acc = fmaf(a[13], r3[1], acc);
            acc = fmaf(a[14], r3[2], acc); acc = fmaf(a[15], r3[3], acc);
            s[j] = acc;
        }
    }

    // Cholesky, shuffle-free: per k, publish residual column k to LDS, read it
    // back (broadcast), scale, republish final G column. invd kept in registers
    // (every lane sees every diagonal).
    float invd[16];
    float ent = 0.0f;
    #pragma unroll
    for (int k = 0; k < 16; ++k) {
        Gc[k * 16 + li] = s[k];                    // residual column k (row li)
        f4 c0 = *(const f4*)&Gc[k * 16 + 0];
        f4 c1 = *(const f4*)&Gc[k * 16 + 4];
        f4 c2 = *(const f4*)&Gc[k * 16 + 8];
        f4 c3 = *(const f4*)&Gc[k * 16 + 12];
        float cc[16] = { c0[0],c0[1],c0[2],c0[3], c1[0],c1[1],c1[2],c1[3],
                         c2[0],c2[1],c2[2],c2[3], c3[0],c3[1],c3[2],c3[3] };
        float dkk = fmaxf(cc[k], 1e-20f);
        float inv = rsqrtf(dkk);
        invd[k] = inv;
        if (li == k) ent = 0.5f * __logf(dkk);
        s[k] *= inv;                               // final G[li][k]
        Gc[k * 16 + li] = s[k];                    // publish final column k
        #pragma unroll
        for (int j = k + 1; j < 16; ++j)
            s[j] = fmaf(-s[k], cc[j] * inv, s[j]); // trailing update
    }

    // P = G^{-1} A, column-oriented: lane li owns column li of A/P.
    // G columns are contiguous broadcast reads (prefetchable, no shuffles).
    {
        float p[16];
        #pragma unroll
        for (int i = 0; i < 16; ++i) p[i] = At[i * RS_A + li];   // A[i][li]
        #pragma unroll
        for (int m = 0; m < 16; ++m) {
            f4 c0 = *(const f4*)&Gc[m * 16 + 0];
            f4 c1 = *(const f4*)&Gc[m * 16 + 4];
            f4 c2 = *(const f4*)&Gc[m * 16 + 8];
            f4 c3 = *(const f4*)&Gc[m * 16 + 12];
            float cc[16] = { c0[0],c0[1],c0[2],c0[3], c1[0],c1[1],c1[2],c1[3],
                             c2[0],c2[1],c2[2],c2[3], c3[0],c3[1],c3[2],c3[3] };
            p[m] *= invd[m];
            #pragma unroll
            for (int j = m + 1; j < 16; ++j)
                p[j] = fmaf(-cc[j], p[m], p[j]);
        }
        // store P back to the A tile (transposed write: lane li owns column li)
        #pragma unroll
        for (int k = 0; k < 16; ++k) At[k * RS_A + li] = p[k];
    }

    // C = BBChol * P, row li (reads P rows broadcast from the A tile)
    float cr[16];
    {
        float bt[16];
        bh8 br0 = *(const bh8*)&Bt_[li * 16];
        bh8 br1 = *(const bh8*)&Bt_[li * 16 + 8];
        #pragma unroll
        for (int k = 0; k < 8; ++k) {
            bt[k]     = bf2f((unsigned short)br0[k]);
            bt[k + 8] = bf2f((unsigned short)br1[k]);
        }
        #pragma unroll
        for (int j = 0; j < 16; ++j) cr[j] = 0.0f;
        #pragma unroll
        for (int k = 0; k < 16; ++k) {
            f4 q0 = *(const f4*)&At[k * RS_A + 0];
            f4 q1 = *(const f4*)&At[k * RS_A + 4];
            f4 q2 = *(const f4*)&At[k * RS_A + 8];
            f4 q3 = *(const f4*)&At[k * RS_A + 12];
            float bk = bt[k];
            cr[0]  = fmaf(bk, q0[0], cr[0]);  cr[1]  = fmaf(bk, q0[1], cr[1]);
            cr[2]  = fmaf(bk, q0[2], cr[2]);  cr[3]  = fmaf(bk, q0[3], cr[3]);
            cr[4]  = fmaf(bk, q1[0], cr[4]);  cr[5]  = fmaf(bk, q1[1], cr[5]);
            cr[6]  = fmaf(bk, q1[2], cr[6]);  cr[7]  = fmaf(bk, q1[3], cr[7]);
            cr[8]  = fmaf(bk, q2[0], cr[8]);  cr[9]  = fmaf(bk, q2[1], cr[9]);
            cr[10] = fmaf(bk, q2[2], cr[10]); cr[11] = fmaf(bk, q2[3], cr[11]);
            cr[12] = fmaf(bk, q3[0], cr[12]); cr[13] = fmaf(bk, q3[1], cr[13]);
            cr[14] = fmaf(bk, q3[2], cr[14]); cr[15] = fmaf(bk, q3[3], cr[15]);
        }
    }

    // N = -G^{-T} C^T (lane li = column li), u = G^{-T} b (replicated).
    // Row i of G^T = column i of G = contiguous LDS read.
    float n_[16], uu[16];
    #pragma unroll
    for (int ii = 0; ii < 16; ++ii) {
        const int i = 15 - ii;
        f4 c0 = *(const f4*)&Gc[i * 16 + 0];
        f4 c1 = *(const f4*)&Gc[i * 16 + 4];
        f4 c2 = *(const f4*)&Gc[i * 16 + 8];
        f4 c3 = *(const f4*)&Gc[i * 16 + 12];
        float cc[16] = { c0[0],c0[1],c0[2],c0[3], c1[0],c1[1],c1[2],c1[3],
                         c2[0],c2[1],c2[2],c2[3], c3[0],c3[1],c3[2],c3[3] };
        float accN = -cr[i];
        float accU = ns[(size_t)t * 16 + i];
        #pragma unroll
        for (int m = i + 1; m < 16; ++m) {
            accN = fmaf(-cc[m], n_[m], accN);   // cc[m] = G[m][i]
            accU = fmaf(-cc[m], uu[m], accU);
        }
        n_[i] = accN * invd[i];
        uu[i] = accU * invd[i];
    }

    if (t < T_LEN - 1) {
        #pragma unroll
        for (int i = 0; i < 16; ++i)
            Nbuf[(size_t)t * 256 + i * 16 + li] = f2bf(n_[i]);   // bf16 N[t][i][j]
    }
    if (li == 0) {
        f4* U4 = (f4*)&Ubuf[(size_t)t * 16];
        f4 u0 = { uu[0], uu[1], uu[2], uu[3] };
        f4 u1 = { uu[4], uu[5], uu[6], uu[7] };
        f4 u2 = { uu[8], uu[9], uu[10], uu[11] };
        f4 u3 = { uu[12], uu[13], uu[14], uu[15] };
        U4[0] = u0; U4[1] = u1; U4[2] = u2; U4[3] = u3;
    }

    // entropy: reduce across the wave, one atomic per wave
    float esum = ent;
    #pragma unroll
    for (int off = 1; off < 64; off <<= 1)
        esum += __shfl_xor(esum, off, 64);
    if ((tid & 63) == 0) atomicAdd(entOut, -esum);
}

// ---- backward recurrence x_t = u_t + N_t x_{t+1}, overlapped chunks ----
__global__ __launch_bounds__(64, 1)
void vilds_stage2(const unsigned short* __restrict__ Nbuf, const float* __restrict__ Ubuf,
                  const float* __restrict__ PXbuf, float* __restrict__ out)
{
    const int lane = threadIdx.x;
    const int i  = lane & 15;   // output row
    const int gq = lane >> 4;   // k-quarter (4 columns each)
    const int a  = blockIdx.x * K2;
    int ts = a + K2 - 1 + W2;
    if (ts > T_LEN - 1) ts = T_LEN - 1;

    float x = Ubuf[(size_t)ts * 16 + i];   // exact at t=T-1, truncated start otherwise
    if (ts < a + K2 && gq == 0)
        out[1 + (size_t)ts * 16 + i] = x + PXbuf[(size_t)ts * 16 + i];

    ushort4 nb[PF]; float ub[PF], pxb[PF];
    #pragma unroll
    for (int q = 0; q < PF; ++q) {
        int tt = ts - 1 - q;
        if (tt >= a) {
            nb[q]  = *(const ushort4*)&Nbuf[(size_t)tt * 256 + i * 16 + gq * 4];
            ub[q]  = Ubuf[(size_t)tt * 16 + i];
            pxb[q] = PXbuf[(size_t)tt * 16 + i];
        }
    }

    for (int tb = ts - 1; tb >= a; tb -= PF) {
        #pragma unroll
        for (int q = 0; q < PF; ++q) {
            int t = tb - q;
            if (t >= a) {
                ushort4 nr = nb[q]; float ut = ub[q]; float pxt = pxb[q];
                int tp = t - PF;
                if (tp >= a) {   // prefetch PF steps ahead
                    nb[q]  = *(const ushort4*)&Nbuf[(size_t)tp * 256 + i * 16 + gq * 4];
                    ub[q]  = Ubuf[(size_t)tp * 16 + i];
                    pxb[q] = PXbuf[(size_t)tp * 16 + i];
                }
                float n0 = bf2f(nr.x), n1 = bf2f(nr.y), n2 = bf2f(nr.z), n3 = bf2f(nr.w);
                float x0 = __shfl(x, 4 * gq + 0, 16);
                float x1 = __shfl(x, 4 * gq + 1, 16);
                float x2 = __shfl(x, 4 * gq + 2, 16);
                float x3 = __shfl(x, 4 * gq + 3, 16);
                float pr = fmaf(n0, x0, n1 * x1);
                pr = fmaf(n2, x2, pr);
                pr = fmaf(n3, x3, pr);
                pr += __shfl_xor(pr, 16);
                pr += __shfl_xor(pr, 32);
                x = ut + pr;                       // x_t[i], replicated over gq
                if (t < a + K2 && gq == 0)
                    out[1 + (size_t)t * 16 + i] = x + pxt;
            }
        }
    }
}

extern "C" void kernel_launch(void* const* d_in, const int* in_sizes, int n_in,
                              void* d_out, int out_size, void* d_ws, size_t ws_size,
                              hipStream_t stream)
{
    const float* data = (const float*)d_in[0];
    const float* Wmu  = (const float*)d_in[1];
    const float* bmu  = (const float*)d_in[2];
    const float* WL   = (const float*)d_in[3];
    const float* bL   = (const float*)d_in[4];
    const float* WLx  = (const float*)d_in[5];
    const float* bLx  = (const float*)d_in[6];
    const float* ns   = (const float*)d_in[7];
    float* out = (float*)d_out;

    unsigned short* Nbuf = (unsigned short*)d_ws;                 // T*256 bf16
    float* Ubuf  = (float*)(Nbuf + (size_t)T_LEN * 256);          // T*16 f32
    float* PXbuf = Ubuf + (size_t)T_LEN * 16;                     // T*16 f32
    short* Wsw   = (short*)(PXbuf + (size_t)T_LEN * 16);          // 66*512 bf16

    hipMemsetAsync(d_out, 0, sizeof(float), stream); // zero entropy accumulator
    wswz_kernel<<<dim3(132), dim3(256), 0, stream>>>(Wmu, WL, WLx, Wsw);
    vilds_fused<<<dim3(T_LEN / 16), dim3(256), 0, stream>>>(
        data, Wsw, bmu, bL, bLx, ns, Nbuf, Ubuf, PXbuf, out);
    vilds_stage2<<<dim3(T_LEN / K2), dim3(64), 0, stream>>>(Nbuf, Ubuf, PXbuf, out);
}